// Round 5
// baseline (160.069 us; speedup 1.0000x reference)
//
#include <hip/hip_runtime.h>

#define BATCH   131072
#define DT      0.01f

// ext_vector type so __builtin_nontemporal_load/store accept it
using f4 = __attribute__((ext_vector_type(4))) float;

// Row layout (float4 units, 32 per row):
//   x:      [0..15]  complex (pair p at cols 2p,2p+1)   [16..31] real
//   Lambda: [0..7]   mu      [8..15] omega              [16..31] lam
// Mapping: 8 threads per row. Thread j (0..7):
//   mu4  = L4[j]      -> pairs 4j..4j+3
//   om4  = L4[8+j]
//   xc   = x4[2j], x4[2j+1]   (complex cols 8j..8j+7)
//   lam  = L4[16+2j], L4[17+2j]; xr = x4[16+2j], x4[17+2j]
// All accesses 16 B, lane-contiguous within each 8-lane group, nontemporal.
__global__ __launch_bounds__(256) void
koopman_kernel(const f4* __restrict__ x4,
               const f4* __restrict__ L4,
               f4* __restrict__ out4)
{
    int t    = blockIdx.x * blockDim.x + threadIdx.x;   // [0, BATCH*8)
    int row  = t >> 3;
    int j    = t & 7;
    int base = row * 32;

    // ---- 8 independent nontemporal dwordx4 loads ----
    f4 mu  = __builtin_nontemporal_load(L4 + base + j);
    f4 om  = __builtin_nontemporal_load(L4 + base + 8 + j);
    f4 xa  = __builtin_nontemporal_load(x4 + base + 2 * j);
    f4 xb  = __builtin_nontemporal_load(x4 + base + 2 * j + 1);
    f4 l0  = __builtin_nontemporal_load(L4 + base + 16 + 2 * j);
    f4 l1  = __builtin_nontemporal_load(L4 + base + 17 + 2 * j);
    f4 xr0 = __builtin_nontemporal_load(x4 + base + 16 + 2 * j);
    f4 xr1 = __builtin_nontemporal_load(x4 + base + 17 + 2 * j);

    // ---- complex: pair k scaled by exp(mu_k dt), rotated by om_k dt ----
    float e0 = __expf(mu.x * DT), e1 = __expf(mu.y * DT);
    float e2 = __expf(mu.z * DT), e3 = __expf(mu.w * DT);
    float s0, c0, s1, c1, s2, c2, s3, c3;
    __sincosf(om.x * DT, &s0, &c0);
    __sincosf(om.y * DT, &s1, &c1);
    __sincosf(om.z * DT, &s2, &c2);
    __sincosf(om.w * DT, &s3, &c3);

    f4 oa, ob;
    oa.x = e0 * (c0 * xa.x - s0 * xa.y);
    oa.y = e0 * (s0 * xa.x + c0 * xa.y);
    oa.z = e1 * (c1 * xa.z - s1 * xa.w);
    oa.w = e1 * (s1 * xa.z + c1 * xa.w);
    ob.x = e2 * (c2 * xb.x - s2 * xb.y);
    ob.y = e2 * (s2 * xb.x + c2 * xb.y);
    ob.z = e3 * (c3 * xb.z - s3 * xb.w);
    ob.w = e3 * (s3 * xb.z + c3 * xb.w);

    // ---- real ----
    f4 or0, or1;
    or0.x = __expf(l0.x * DT) * xr0.x;
    or0.y = __expf(l0.y * DT) * xr0.y;
    or0.z = __expf(l0.z * DT) * xr0.z;
    or0.w = __expf(l0.w * DT) * xr0.w;
    or1.x = __expf(l1.x * DT) * xr1.x;
    or1.y = __expf(l1.y * DT) * xr1.y;
    or1.z = __expf(l1.z * DT) * xr1.z;
    or1.w = __expf(l1.w * DT) * xr1.w;

    // ---- 4 nontemporal dwordx4 stores ----
    __builtin_nontemporal_store(oa,  out4 + base + 2 * j);
    __builtin_nontemporal_store(ob,  out4 + base + 2 * j + 1);
    __builtin_nontemporal_store(or0, out4 + base + 16 + 2 * j);
    __builtin_nontemporal_store(or1, out4 + base + 17 + 2 * j);
}

extern "C" void kernel_launch(void* const* d_in, const int* in_sizes, int n_in,
                              void* d_out, int out_size, void* d_ws, size_t ws_size,
                              hipStream_t stream)
{
    const f4* x4 = (const f4*)d_in[0];
    const f4* L4 = (const f4*)d_in[1];
    f4* out4     = (f4*)d_out;

    const int total_threads = BATCH * 8;     // 1,048,576
    const int block = 256;
    const int grid  = total_threads / block; // 4096

    koopman_kernel<<<grid, block, 0, stream>>>(x4, L4, out4);
}